// Round 2
// 826.177 us; speedup vs baseline: 1.0611x; 1.0611x over previous
//
#include <hip/hip_runtime.h>

// Problem: multi-adapter batched LoRA
// B=16, S=1024, H=4096, O=4096, N=8, R=64; all fp32.
// out = result + ((data*mask)*scal[n]) @ A_n^T @ B_n^T, adapter n owns 2048 rows.
//
// Fused single-pass design:
//   grid = 1024 blocks (one per 16-row tile), 512 threads = 8 waves.
//   Phase 1: waves split K (8 x 512), MFMA partials -> LDS reduce -> bf16 t in LDS.
//   Phase 2: waves split O (8 x 512), t frags in regs, stream result->out.
// Rationale: two-kernel version was latency-serialized (2048 waves, 22% occ,
// ~7900 cyc/iter). This gives 8192 waves + unrolled loads for MLP, and removes
// the 16MB tpart intermediate entirely.
// NOTE: round-1 bench was an infra failure (container died twice, no counters);
// source audited for hang/fault sources (LDS 36KB<64KB, all loads 16B-aligned,
// uniform barriers, bounded indices) and resubmitted.

#define B_   16
#define S_   1024
#define H_   4096
#define O_   4096
#define N_   8
#define R_   64
#define ROWS (B_ * S_)                 // 16384
#define ROWS_PER_ADAPTER (ROWS / N_)   // 2048

typedef __attribute__((ext_vector_type(8))) short s8v;  // 8 bf16 (4 VGPRs) - MFMA A/B frag
typedef __attribute__((ext_vector_type(4))) float f4v;  // MFMA C/D frag

// round-to-nearest-even fp32 -> bf16 (bit pattern in a short)
static __device__ __forceinline__ short f2bf(float f) {
    union { float f; unsigned u; } v; v.f = f;
    unsigned r = (v.u + 0x7FFFu + ((v.u >> 16) & 1u)) >> 16;
    return (short)r;
}

// ---------------------------------------------------------------------------
// Prologue: convert lora_a (x scaling folded in) and lora_b to bf16 in ws.
// A elems = N*R*H = 2M, B elems = N*O*R = 2M. 4 elems/thread -> 1M threads.
__global__ void cvt_weights(const float* __restrict__ la,
                            const float* __restrict__ lb,
                            const float* __restrict__ scal,
                            short* __restrict__ abf,
                            short* __restrict__ bbf) {
    const int i = blockIdx.x * blockDim.x + threadIdx.x;   // float4 index
    const int A_ELEMS4 = (N_ * R_ * H_) / 4;               // 524288
    if (i < A_ELEMS4) {
        const int n = i / ((R_ * H_) / 4);                 // i / 65536
        const float s = scal[n];
        float4 v = ((const float4*)la)[i];
        short4 o;
        o.x = f2bf(v.x * s); o.y = f2bf(v.y * s);
        o.z = f2bf(v.z * s); o.w = f2bf(v.w * s);
        ((short4*)abf)[i] = o;
    } else {
        const int j = i - A_ELEMS4;
        float4 v = ((const float4*)lb)[j];
        short4 o;
        o.x = f2bf(v.x); o.y = f2bf(v.y);
        o.z = f2bf(v.z); o.w = f2bf(v.w);
        ((short4*)bbf)[j] = o;
    }
}

// ---------------------------------------------------------------------------
// Fused LoRA: block = 16 rows, 512 threads = 8 waves.
// Phase 1: wave w reduces K-slice [w*512, w*512+512) into t-partials (MFMA).
//          All-wave LDS reduce -> t[16][64] bf16 in LDS.
// Phase 2: wave w computes out-slice O in [w*512, w*512+512) from t (in regs) and B.
__global__ __launch_bounds__(512, 4)
void lora_fused(const float* __restrict__ data, const float* __restrict__ mask,
                const short* __restrict__ abf, const short* __restrict__ bbf,
                const float* __restrict__ result, float* __restrict__ out) {
    __shared__ float part[8][16][66];   // per-wave t-partials, +2 pad kills bank conflicts
    __shared__ short tl[16][80];        // final bf16 t, padded rows (16B-aligned frags)

    const int tile = blockIdx.x;
    const int row0 = tile * 16;
    const int n    = row0 / ROWS_PER_ADAPTER;   // adapter index (128 tiles per adapter)
    const int tid  = threadIdx.x;
    const int w    = tid >> 6;                  // wave 0..7
    const int lane = tid & 63;
    const int ml   = lane & 15;                 // MFMA m/n lane index
    const int g    = lane >> 4;                 // quad -> k offset g*8, row group g*4

    // ---------------- phase 1: t-partial[w] = x[16 rows, K-slice] @ A^T ----------------
    const int row = row0 + ml;
    const int k0  = w * 512 + g * 8;
    const float* dptr = data + (size_t)row * H_ + k0;
    const float* mptr = mask + (size_t)row * H_ + k0;
    const short* ap0 = abf + (size_t)(n * R_ +  0 + ml) * H_ + k0;
    const short* ap1 = abf + (size_t)(n * R_ + 16 + ml) * H_ + k0;
    const short* ap2 = abf + (size_t)(n * R_ + 32 + ml) * H_ + k0;
    const short* ap3 = abf + (size_t)(n * R_ + 48 + ml) * H_ + k0;

    f4v acc0 = {0.f, 0.f, 0.f, 0.f};
    f4v acc1 = {0.f, 0.f, 0.f, 0.f};
    f4v acc2 = {0.f, 0.f, 0.f, 0.f};
    f4v acc3 = {0.f, 0.f, 0.f, 0.f};

#pragma unroll 2
    for (int ks = 0; ks < 512 / 32; ++ks) {
        float4 d0 = *(const float4*)(dptr);
        float4 d1 = *(const float4*)(dptr + 4);
        float4 m0 = *(const float4*)(mptr);
        float4 m1 = *(const float4*)(mptr + 4);
        s8v a0 = *(const s8v*)(ap0);
        s8v a1 = *(const s8v*)(ap1);
        s8v a2 = *(const s8v*)(ap2);
        s8v a3 = *(const s8v*)(ap3);

        s8v xf;
        xf[0] = f2bf(d0.x * m0.x); xf[1] = f2bf(d0.y * m0.y);
        xf[2] = f2bf(d0.z * m0.z); xf[3] = f2bf(d0.w * m0.w);
        xf[4] = f2bf(d1.x * m1.x); xf[5] = f2bf(d1.y * m1.y);
        xf[6] = f2bf(d1.z * m1.z); xf[7] = f2bf(d1.w * m1.w);

        acc0 = __builtin_amdgcn_mfma_f32_16x16x32_bf16(xf, a0, acc0, 0, 0, 0);
        acc1 = __builtin_amdgcn_mfma_f32_16x16x32_bf16(xf, a1, acc1, 0, 0, 0);
        acc2 = __builtin_amdgcn_mfma_f32_16x16x32_bf16(xf, a2, acc2, 0, 0, 0);
        acc3 = __builtin_amdgcn_mfma_f32_16x16x32_bf16(xf, a3, acc3, 0, 0, 0);

        dptr += 32; mptr += 32;
        ap0 += 32; ap1 += 32; ap2 += 32; ap3 += 32;
    }

    // C/D layout (16x16x32): col = lane&15, row = (lane>>4)*4 + reg
#pragma unroll
    for (int i = 0; i < 4; ++i) {
        part[w][g * 4 + i][ 0 + ml] = acc0[i];
        part[w][g * 4 + i][16 + ml] = acc1[i];
        part[w][g * 4 + i][32 + ml] = acc2[i];
        part[w][g * 4 + i][48 + ml] = acc3[i];
    }
    __syncthreads();

    // ---------------- reduce 8 partials -> bf16 t in LDS ----------------
    {
        const int e0 = tid * 2;        // 1024 elems of [16][64], 2 per thread
        const int rw = e0 >> 6;
        const int c  = e0 & 63;
        float s0 = 0.f, s1 = 0.f;
#pragma unroll
        for (int p = 0; p < 8; ++p) {
            float2 v = *(const float2*)&part[p][rw][c];
            s0 += v.x; s1 += v.y;
        }
        tl[rw][c]     = f2bf(s0);
        tl[rw][c + 1] = f2bf(s1);
    }
    __syncthreads();

    // ---------------- phase 2: out = result + t @ B^T ----------------
    // A-frag: t rows (m=ml), k = r; held in regs for all 32 o-tiles of this wave.
    s8v tf0 = *(const s8v*)&tl[ml][g * 8];
    s8v tf1 = *(const s8v*)&tl[ml][g * 8 + 32];

    // B-frag: lane n-index = o_local = ml, k = r = g*8+j; Bbf row-major [n][o][r]
    const short* bptr = bbf + ((size_t)n * O_ + w * 512 + ml) * R_ + g * 8;
    const size_t obase0 = (size_t)(row0 + g * 4) * O_ + w * 512 + ml;

#pragma unroll 2
    for (int ot = 0; ot < 32; ++ot) {
        s8v bf0 = *(const s8v*)(bptr);
        s8v bf1 = *(const s8v*)(bptr + 32);
        f4v acc = {0.f, 0.f, 0.f, 0.f};
        acc = __builtin_amdgcn_mfma_f32_16x16x32_bf16(tf0, bf0, acc, 0, 0, 0);
        acc = __builtin_amdgcn_mfma_f32_16x16x32_bf16(tf1, bf1, acc, 0, 0, 0);

        const size_t base = obase0 + (size_t)ot * 16;
#pragma unroll
        for (int i = 0; i < 4; ++i) {
            out[base + (size_t)i * O_] = result[base + (size_t)i * O_] + acc[i];
        }
        bptr += 16 * R_;   // next 16 o-rows
    }
}

// ---------------------------------------------------------------------------
extern "C" void kernel_launch(void* const* d_in, const int* in_sizes, int n_in,
                              void* d_out, int out_size, void* d_ws, size_t ws_size,
                              hipStream_t stream) {
    const float* result = (const float*)d_in[0];
    const float* data   = (const float*)d_in[1];
    const float* mask   = (const float*)d_in[2];
    const float* lora_a = (const float*)d_in[3];
    const float* lora_b = (const float*)d_in[4];
    const float* scal   = (const float*)d_in[5];
    float* out = (float*)d_out;

    // ws layout: A_bf16 (4MB) | B_bf16 (4MB)
    short* abf = (short*)d_ws;
    short* bbf = abf + (size_t)N_ * R_ * H_;

    const int cvt_threads = (N_ * R_ * H_ + N_ * O_ * R_) / 4;   // 1M
    cvt_weights<<<cvt_threads / 256, 256, 0, stream>>>(lora_a, lora_b, scal, abf, bbf);
    lora_fused<<<dim3(ROWS / 16), 512, 0, stream>>>(data, mask, abf, bbf, result, out);
}